// Round 15
// baseline (123.620 us; speedup 1.0000x reference)
//
#include <hip/hip_runtime.h>
#include <hip/hip_fp16.h>

#define NEG_SLOPE 0.01f
typedef unsigned int uint;
typedef unsigned short u16;

#define NBK 256          // max buckets (N <= 65536); actual = ceil(N/256)
#define CHUNK 4096       // edges per partition workgroup
#define KPT 16           // edges per thread (CHUNK/256)
#define GROWS 16         // rows per wave in the register GEMMs

// unpack uint4 (8 halves) and FMA into 8 accumulators
__device__ __forceinline__ void acc8(uint4 v, float w, float* a) {
    float2 f;
    f = __half22float2(*reinterpret_cast<__half2*>(&v.x)); a[0] = fmaf(f.x, w, a[0]); a[1] = fmaf(f.y, w, a[1]);
    f = __half22float2(*reinterpret_cast<__half2*>(&v.y)); a[2] = fmaf(f.x, w, a[2]); a[3] = fmaf(f.y, w, a[3]);
    f = __half22float2(*reinterpret_cast<__half2*>(&v.z)); a[4] = fmaf(f.x, w, a[4]); a[5] = fmaf(f.y, w, a[5]);
    f = __half22float2(*reinterpret_cast<__half2*>(&v.w)); a[6] = fmaf(f.x, w, a[6]); a[7] = fmaf(f.y, w, a[7]);
}

__device__ __forceinline__ void unpack8(uint4 v, float* s) {
    float2 f;
    f = __half22float2(*reinterpret_cast<__half2*>(&v.x)); s[0] = f.x; s[1] = f.y;
    f = __half22float2(*reinterpret_cast<__half2*>(&v.y)); s[2] = f.x; s[3] = f.y;
    f = __half22float2(*reinterpret_cast<__half2*>(&v.z)); s[4] = f.x; s[5] = f.y;
    f = __half22float2(*reinterpret_cast<__half2*>(&v.w)); s[6] = f.x; s[7] = f.y;
}

// ---- fused: register GEMM1 (fp32 in -> fp16 planes) + per-chunk histogram ----
__global__ __launch_bounds__(256) void gemm1_hist(const float* __restrict__ X,
                                                  const float* __restrict__ W,
                                                  __half* __restrict__ H, int N,
                                                  const int* __restrict__ dst,
                                                  uint* __restrict__ hist, int E,
                                                  int gblocks) {
    __shared__ uint lh[NBK];
    if ((int)blockIdx.x >= gblocks) {
        int cb = (int)blockIdx.x - gblocks;
        int t = threadIdx.x;
        lh[t] = 0u;
        __syncthreads();
        int base = cb * CHUNK;
#pragma unroll
        for (int r = 0; r < 4; ++r) {
            int e4 = base + r * 1024 + t * 4;
            if (e4 + 3 < E) {
                int4 d = *(const int4*)(dst + e4);
                atomicAdd(&lh[((uint)d.x) >> 8], 1u);
                atomicAdd(&lh[((uint)d.y) >> 8], 1u);
                atomicAdd(&lh[((uint)d.z) >> 8], 1u);
                atomicAdd(&lh[((uint)d.w) >> 8], 1u);
            } else {
                for (int e = e4; e < E && e < e4 + 4; ++e)
                    atomicAdd(&lh[((uint)dst[e]) >> 8], 1u);
            }
        }
        __syncthreads();
        hist[(size_t)cb * NBK + t] = lh[t];
        return;
    }
    // ---- GEMM part ----
    int lane = threadIdx.x & 63;
    int wv = threadIdx.x >> 6;
    float wc[64];
#pragma unroll
    for (int k = 0; k < 64; ++k) wc[k] = W[k * 64 + lane];
    size_t plane = (size_t)(lane >> 5) * ((size_t)N * 32);
    int c = lane & 31;
    int rowBase = ((int)blockIdx.x * 4 + wv) * GROWS;
    for (int g = 0; g < GROWS; g += 4) {
        int r0 = __builtin_amdgcn_readfirstlane(rowBase + g);
        if (r0 >= N) return;
        int e1 = min(r0 + 1, N - 1), e2 = min(r0 + 2, N - 1), e3 = min(r0 + 3, N - 1);
        const float* x0 = X + (size_t)r0 * 64;
        const float* x1 = X + (size_t)e1 * 64;
        const float* x2 = X + (size_t)e2 * 64;
        const float* x3 = X + (size_t)e3 * 64;
        float a0 = 0.f, a1 = 0.f, a2 = 0.f, a3 = 0.f;
        float b0 = 0.f, b1 = 0.f, b2 = 0.f, b3 = 0.f;
#pragma unroll
        for (int k = 0; k < 64; k += 2) {
            a0 = fmaf(x0[k], wc[k], a0); b0 = fmaf(x0[k + 1], wc[k + 1], b0);
            a1 = fmaf(x1[k], wc[k], a1); b1 = fmaf(x1[k + 1], wc[k + 1], b1);
            a2 = fmaf(x2[k], wc[k], a2); b2 = fmaf(x2[k + 1], wc[k + 1], b2);
            a3 = fmaf(x3[k], wc[k], a3); b3 = fmaf(x3[k + 1], wc[k + 1], b3);
        }
        H[plane + (size_t)r0 * 32 + c] = __float2half(a0 + b0);
        if (r0 + 1 < N) H[plane + (size_t)(r0 + 1) * 32 + c] = __float2half(a1 + b1);
        if (r0 + 2 < N) H[plane + (size_t)(r0 + 2) * 32 + c] = __float2half(a2 + b2);
        if (r0 + 3 < N) H[plane + (size_t)(r0 + 3) * 32 + c] = __float2half(a3 + b3);
    }
}

// ---- S1: per-bucket column scan of hist (one block per bucket) -> chunk prefixes + buckTotal ----
__global__ __launch_bounds__(256) void scan_hist(uint* __restrict__ hist,
                                                 uint* __restrict__ buckTotal,
                                                 int nchunks) {
    __shared__ uint lds[256];
    int b = blockIdx.x;
    int t = threadIdx.x;
    uint carry = 0;
    for (int c0 = 0; c0 < nchunks; c0 += 256) {
        int c = c0 + t;
        uint v = (c < nchunks) ? hist[(size_t)c * NBK + b] : 0u;
        lds[t] = v;
        __syncthreads();
        for (int off = 1; off < 256; off <<= 1) {
            uint u = (t >= off) ? lds[t - off] : 0u;
            __syncthreads();
            lds[t] += u;
            __syncthreads();
        }
        uint incl = lds[t];
        if (c < nchunks) hist[(size_t)c * NBK + b] = carry + incl - v;
        uint tot = lds[255];
        __syncthreads();
        carry += tot;
    }
    if (t == 0) buckTotal[b] = carry;
}

// ---- P: partition edges into reserved bucket runs; bases from buckTotal LDS scan ----
__global__ __launch_bounds__(256) void partition_edges(const int* __restrict__ src,
                                                       const int* __restrict__ dst,
                                                       const uint* __restrict__ hist,
                                                       const uint* __restrict__ buckTotal,
                                                       uint* __restrict__ staging,
                                                       int E) {
    __shared__ uint lh[NBK];
    __shared__ uint sc[NBK];
    __shared__ uint runbase[NBK];
    int t = threadIdx.x;
    lh[t] = 0u;
    uint tot = buckTotal[t];
    sc[t] = tot;
    __syncthreads();
    for (int off = 1; off < NBK; off <<= 1) {
        uint u = (t >= off) ? sc[t - off] : 0u;
        __syncthreads();
        sc[t] += u;
        __syncthreads();
    }
    int base = blockIdx.x * CHUNK;
    uint rec[KPT], rb[KPT], rk[KPT];
#pragma unroll
    for (int r = 0; r < 4; ++r) {
        int e4 = base + r * 1024 + t * 4;
        if (e4 + 3 < E) {
            int4 s = *(const int4*)(src + e4);
            int4 d = *(const int4*)(dst + e4);
            int k = r * 4;
            rb[k + 0] = ((uint)d.x) >> 8; rec[k + 0] = (uint)s.x | (((uint)d.x & 255u) << 16);
            rb[k + 1] = ((uint)d.y) >> 8; rec[k + 1] = (uint)s.y | (((uint)d.y & 255u) << 16);
            rb[k + 2] = ((uint)d.z) >> 8; rec[k + 2] = (uint)s.z | (((uint)d.z & 255u) << 16);
            rb[k + 3] = ((uint)d.w) >> 8; rec[k + 3] = (uint)s.w | (((uint)d.w & 255u) << 16);
            rk[k + 0] = atomicAdd(&lh[rb[k + 0]], 1u);
            rk[k + 1] = atomicAdd(&lh[rb[k + 1]], 1u);
            rk[k + 2] = atomicAdd(&lh[rb[k + 2]], 1u);
            rk[k + 3] = atomicAdd(&lh[rb[k + 3]], 1u);
        } else {
            for (int j = 0; j < 4; ++j) {
                int e = e4 + j;
                int k = r * 4 + j;
                if (e < E) {
                    uint s = (uint)src[e], d = (uint)dst[e];
                    rb[k] = d >> 8;
                    rec[k] = s | ((d & 255u) << 16);
                    rk[k] = atomicAdd(&lh[rb[k]], 1u);
                } else rb[k] = 0xFFFFFFFFu;
            }
        }
    }
    __syncthreads();
    runbase[t] = (sc[t] - tot) + hist[(size_t)blockIdx.x * NBK + t];
    __syncthreads();
#pragma unroll
    for (int k = 0; k < KPT; ++k)
        if (rb[k] != 0xFFFFFFFFu)
            staging[runbase[rb[k]] + rk[k]] = rec[k];
}

// ---- B: per-bucket CSR build: srcIdx (u16), offs, dinv; base from buckTotal LDS scan ----
__global__ __launch_bounds__(256) void build_csr(const uint* __restrict__ staging,
                                                 const uint* __restrict__ buckTotal,
                                                 u16* __restrict__ srcIdx,
                                                 uint* __restrict__ offs,
                                                 float* __restrict__ dinv,
                                                 int N, int nbuck) {
    __shared__ uint nh[256];
    __shared__ uint nstart[256];
    __shared__ u16 rankbuf[8192];
    __shared__ u16 outbuf[8192];
    int b = blockIdx.x;
    int t = threadIdx.x;
    uint tot = buckTotal[t];
    nstart[t] = tot;
    __syncthreads();
    for (int off = 1; off < NBK; off <<= 1) {
        uint u = (t >= off) ? nstart[t - off] : 0u;
        __syncthreads();
        nstart[t] += u;
        __syncthreads();
    }
    uint endb = nstart[b];
    uint base = endb - buckTotal[b];
    __syncthreads();
    uint T = endb - base;
    nh[t] = 0u;
    __syncthreads();
    for (uint i = t; i < T; i += 256) {
        uint rec = staging[base + i];
        rankbuf[i] = (u16)atomicAdd(&nh[(rec >> 16) & 255u], 1u);
    }
    __syncthreads();
    uint deg = nh[t];
    nstart[t] = deg;
    __syncthreads();
    for (int off = 1; off < 256; off <<= 1) {
        uint u = (t >= off) ? nstart[t - off] : 0u;
        __syncthreads();
        nstart[t] += u;
        __syncthreads();
    }
    uint excl = nstart[t] - deg;
    __syncthreads();
    nstart[t] = excl;
    __syncthreads();
    for (uint i = t; i < T; i += 256) {
        uint rec = staging[base + i];
        outbuf[nstart[(rec >> 16) & 255u] + rankbuf[i]] = (u16)(rec & 0xFFFFu);
    }
    __syncthreads();
    for (uint i = t; i < T; i += 256) srcIdx[base + i] = outbuf[i];
    int node = b * 256 + t;
    if (node < N) {
        offs[node] = base + excl;
        dinv[node] = rsqrtf((float)(deg + 1u));
    }
    if (b == nbuck - 1 && t == 0) offs[N] = endb;
}

// ---- shared agg inner loop: contiguous run [beg,end), u16 index stream + dinv gather ----
// all 4 lanes of a group read the same srcIdx uint4 (8 edges, broadcast);
// dinv[s] is group-broadcast (1 txn) and issued in parallel with the row gather
__device__ __forceinline__ void agg_run(const u16* __restrict__ sidx,
                                        const float* __restrict__ dinv,
                                        const uint4* __restrict__ h8,
                                        uint beg, uint end, int q, float* a) {
    uint p = beg;
    uint pa = (p + 7u) & ~7u;
    if (pa > end) pa = end;
    for (; p < pa; ++p) {
        uint s = sidx[p];
        float w = dinv[s];
        uint4 v = h8[(size_t)s * 4 + q];
        acc8(v, w, a);
    }
    for (; p + 8 <= end; p += 8) {
        uint4 e = *(const uint4*)(sidx + p);
        uint s0 = e.x & 0xFFFFu, s1 = e.x >> 16;
        uint s2 = e.y & 0xFFFFu, s3 = e.y >> 16;
        uint s4 = e.z & 0xFFFFu, s5 = e.z >> 16;
        uint s6 = e.w & 0xFFFFu, s7 = e.w >> 16;
        float w0 = dinv[s0], w1 = dinv[s1], w2 = dinv[s2], w3 = dinv[s3];
        float w4 = dinv[s4], w5 = dinv[s5], w6 = dinv[s6], w7 = dinv[s7];
        uint4 v0 = h8[(size_t)s0 * 4 + q];
        uint4 v1 = h8[(size_t)s1 * 4 + q];
        uint4 v2 = h8[(size_t)s2 * 4 + q];
        uint4 v3 = h8[(size_t)s3 * 4 + q];
        uint4 v4 = h8[(size_t)s4 * 4 + q];
        uint4 v5 = h8[(size_t)s5 * 4 + q];
        uint4 v6 = h8[(size_t)s6 * 4 + q];
        uint4 v7 = h8[(size_t)s7 * 4 + q];
        acc8(v0, w0, a);
        acc8(v1, w1, a);
        acc8(v2, w2, a);
        acc8(v3, w3, a);
        acc8(v4, w4, a);
        acc8(v5, w5, a);
        acc8(v6, w6, a);
        acc8(v7, w7, a);
    }
    for (; p < end; ++p) {
        uint s = sidx[p];
        float w = dinv[s];
        uint4 v = h8[(size_t)s * 4 + q];
        acc8(v, w, a);
    }
}

// ---------------- layer-1 aggregation: 4-lane group per node, plane-split ----------------
__global__ __launch_bounds__(256) void agg1(const __half* __restrict__ h,
                                            const uint* __restrict__ offs,
                                            const u16* __restrict__ srcIdx,
                                            const float* __restrict__ dinv,
                                            const float* __restrict__ b,
                                            const float* __restrict__ mask,
                                            __half* __restrict__ outp,
                                            int N, int nbA) {
    int pl = ((int)blockIdx.x >= nbA) ? 1 : 0;
    int blk = (int)blockIdx.x - pl * nbA;
    int lane = threadIdx.x & 63;
    int wid = threadIdx.x >> 6;
    int g = lane >> 2;
    int q = lane & 3;
    int node = blk * 64 + wid * 16 + g;
    bool valid = node < N;
    uint beg = 0, end = 0;
    if (valid) { beg = offs[node]; end = offs[node + 1]; }
    const uint4* h8 = (const uint4*)(h + (size_t)pl * N * 32);
    float a[8] = {0.f, 0.f, 0.f, 0.f, 0.f, 0.f, 0.f, 0.f};
    agg_run(srcIdx, dinv, h8, beg, end, q, a);
    if (valid) {
        float dv = dinv[node];
        float dv2 = dv * dv;
        float s[8];
        unpack8(h8[(size_t)node * 4 + q], s);
        const float4* b4 = (const float4*)b;
        float4 bv0 = b4[pl * 8 + q * 2];
        float4 bv1 = b4[pl * 8 + q * 2 + 1];
        const float4* m4 = (const float4*)mask;
        float4 mv0 = m4[(size_t)node * 16 + pl * 8 + q * 2];
        float4 mv1 = m4[(size_t)node * 16 + pl * 8 + q * 2 + 1];
        float bb[8] = {bv0.x, bv0.y, bv0.z, bv0.w, bv1.x, bv1.y, bv1.z, bv1.w};
        float mm[8] = {mv0.x, mv0.y, mv0.z, mv0.w, mv1.x, mv1.y, mv1.z, mv1.w};
        uint4 o;
        uint* op = (uint*)&o;
#pragma unroll
        for (int i = 0; i < 4; ++i) {
            float v0 = a[2 * i] * dv + s[2 * i] * dv2 + bb[2 * i];
            float v1 = a[2 * i + 1] * dv + s[2 * i + 1] * dv2 + bb[2 * i + 1];
            v0 = (v0 > 0.f) ? v0 : NEG_SLOPE * v0;
            v1 = (v1 > 0.f) ? v1 : NEG_SLOPE * v1;
            v0 *= mm[2 * i]; v1 *= mm[2 * i + 1];
            __half2 hh = __floats2half2_rn(v0, v1);
            op[i] = *reinterpret_cast<uint*>(&hh);
        }
        ((uint4*)(outp + (size_t)pl * N * 32))[(size_t)node * 4 + q] = o;
    }
}

// ---------------- register GEMM 2: fp16 plane input (uniform scalar reads), fp16 out ----------------
__global__ __launch_bounds__(256) void gemm64x32(const __half* __restrict__ Xh,
                                                 const float* __restrict__ W,
                                                 __half* __restrict__ H, int N) {
    int lane = threadIdx.x & 63;
    int col = lane & 31;
    int wv = threadIdx.x >> 6;
    size_t N32 = (size_t)N * 32;
    float wc[64];
#pragma unroll
    for (int k = 0; k < 64; ++k) wc[k] = W[k * 32 + col];
    int rowBase = ((int)blockIdx.x * 4 + wv) * GROWS;
    for (int g = 0; g < GROWS; g += 4) {
        int r0 = __builtin_amdgcn_readfirstlane(rowBase + g);
        if (r0 >= N) return;
        int e1 = min(r0 + 1, N - 1), e2 = min(r0 + 2, N - 1), e3 = min(r0 + 3, N - 1);
        float a0 = 0.f, a1 = 0.f, a2 = 0.f, a3 = 0.f;
        float b0 = 0.f, b1 = 0.f, b2 = 0.f, b3 = 0.f;
#pragma unroll
        for (int pl = 0; pl < 2; ++pl) {
            const uint* x0 = (const uint*)(Xh + pl * N32 + (size_t)r0 * 32);
            const uint* x1 = (const uint*)(Xh + pl * N32 + (size_t)e1 * 32);
            const uint* x2 = (const uint*)(Xh + pl * N32 + (size_t)e2 * 32);
            const uint* x3 = (const uint*)(Xh + pl * N32 + (size_t)e3 * 32);
#pragma unroll
            for (int kk = 0; kk < 16; ++kk) {
                uint u0 = x0[kk], u1 = x1[kk], u2 = x2[kk], u3 = x3[kk];
                float2 f0 = __half22float2(*reinterpret_cast<__half2*>(&u0));
                float2 f1 = __half22float2(*reinterpret_cast<__half2*>(&u1));
                float2 f2 = __half22float2(*reinterpret_cast<__half2*>(&u2));
                float2 f3 = __half22float2(*reinterpret_cast<__half2*>(&u3));
                int k0 = pl * 32 + 2 * kk;
                a0 = fmaf(f0.x, wc[k0], a0); b0 = fmaf(f0.y, wc[k0 + 1], b0);
                a1 = fmaf(f1.x, wc[k0], a1); b1 = fmaf(f1.y, wc[k0 + 1], b1);
                a2 = fmaf(f2.x, wc[k0], a2); b2 = fmaf(f2.y, wc[k0 + 1], b2);
                a3 = fmaf(f3.x, wc[k0], a3); b3 = fmaf(f3.y, wc[k0 + 1], b3);
            }
        }
        if (lane < 32) {
            H[(size_t)r0 * 32 + col] = __float2half(a0 + b0);
            if (r0 + 1 < N) H[(size_t)(r0 + 1) * 32 + col] = __float2half(a1 + b1);
            if (r0 + 2 < N) H[(size_t)(r0 + 2) * 32 + col] = __float2half(a2 + b2);
            if (r0 + 3 < N) H[(size_t)(r0 + 3) * 32 + col] = __float2half(a3 + b3);
        }
    }
}

// ---------------- layer-2 aggregation: 4-lane group per node ----------------
__global__ __launch_bounds__(256) void agg2(const __half* __restrict__ h,
                                            const uint* __restrict__ offs,
                                            const u16* __restrict__ srcIdx,
                                            const float* __restrict__ dinv,
                                            const float* __restrict__ b,
                                            float* __restrict__ outp, int N) {
    int lane = threadIdx.x & 63;
    int wid = threadIdx.x >> 6;
    int g = lane >> 2;
    int q = lane & 3;
    int node = (int)blockIdx.x * 64 + wid * 16 + g;
    bool valid = node < N;
    uint beg = 0, end = 0;
    if (valid) { beg = offs[node]; end = offs[node + 1]; }
    const uint4* h8 = (const uint4*)h;
    float a[8] = {0.f, 0.f, 0.f, 0.f, 0.f, 0.f, 0.f, 0.f};
    agg_run(srcIdx, dinv, h8, beg, end, q, a);
    if (valid) {
        float dv = dinv[node];
        float dv2 = dv * dv;
        float s[8];
        unpack8(h8[(size_t)node * 4 + q], s);
        float4 bv0 = ((const float4*)b)[q * 2];
        float4 bv1 = ((const float4*)b)[q * 2 + 1];
        float bb[8] = {bv0.x, bv0.y, bv0.z, bv0.w, bv1.x, bv1.y, bv1.z, bv1.w};
        float o[8];
#pragma unroll
        for (int i = 0; i < 8; ++i) {
            float v = a[i] * dv + s[i] * dv2 + bb[i];
            o[i] = (v > 0.f) ? v : NEG_SLOPE * v;
        }
        float4* outv = (float4*)outp;
        outv[(size_t)node * 8 + q * 2]     = make_float4(o[0], o[1], o[2], o[3]);
        outv[(size_t)node * 8 + q * 2 + 1] = make_float4(o[4], o[5], o[6], o[7]);
    }
}

extern "C" void kernel_launch(void* const* d_in, const int* in_sizes, int n_in,
                              void* d_out, int out_size, void* d_ws, size_t ws_size,
                              hipStream_t stream) {
    const float* x    = (const float*)d_in[0];
    const int*   ei   = (const int*)d_in[1];
    const float* mask = (const float*)d_in[2];
    const float* W1   = (const float*)d_in[3];
    const float* b1   = (const float*)d_in[4];
    const float* W2   = (const float*)d_in[5];
    const float* b2   = (const float*)d_in[6];
    float* out = (float*)d_out;

    const int N = in_sizes[0] / 64;   // 50000 (< 65536: u16 CSR valid)
    const int E = in_sizes[1] / 2;    // 800000
    const int* src = ei;
    const int* dst = ei + E;

    const int nbuck  = (N + 255) >> 8;
    const int chunks = (E + CHUNK - 1) / CHUNK;
    const int gblocks = (N + 4 * GROWS - 1) / (4 * GROWS);
    const int nbA = (N + 63) / 64;    // agg blocks (64 nodes each)

    char* w = (char*)d_ws;
    uint*  hist      = (uint*)w;    w += (size_t)chunks * NBK * 4;
    uint*  buckTotal = (uint*)w;    w += NBK * 4;
    w = (char*)(((size_t)w + 15) & ~15ull);
    uint*  offs      = (uint*)w;    w += (size_t)(N + 1) * 4;
    w = (char*)(((size_t)w + 15) & ~15ull);
    float* dinv      = (float*)w;   w += (size_t)N * 4;
    uint*  staging   = (uint*)w;    w += (size_t)E * 4;
    u16*   srcIdx    = (u16*)w;     w += (((size_t)E * 2 + 15) & ~15ull);
    __half* h1       = (__half*)w;  w += (size_t)N * 64 * 2;   // 2 planes of N*32
    __half* hpost    = (__half*)w;  w += (size_t)N * 64 * 2;   // 2 planes of N*32
    __half* h2       = h1;  // reuse: h1 dead after agg1

    // ---- prep + gemm1 fused; parallel scan; deterministic counting sort ----
    gemm1_hist<<<gblocks + chunks, 256, 0, stream>>>(x, W1, h1, N, dst, hist, E, gblocks);
    scan_hist<<<NBK, 256, 0, stream>>>(hist, buckTotal, chunks);
    partition_edges<<<chunks, 256, 0, stream>>>(src, dst, hist, buckTotal, staging, E);
    build_csr<<<nbuck, 256, 0, stream>>>(staging, buckTotal, srcIdx, offs, dinv, N, nbuck);

    // ---- layer 1 aggregation (plane-split, group-per-node) ----
    agg1<<<2 * nbA, 256, 0, stream>>>(h1, offs, srcIdx, dinv, b1, mask, hpost, N, nbA);

    // ---- layer 2 ----
    gemm64x32<<<gblocks, 256, 0, stream>>>(hpost, W2, h2, N);
    agg2<<<nbA, 256, 0, stream>>>(h2, offs, srcIdx, dinv, b2, out, N);
}

// Round 16
// 115.848 us; speedup vs baseline: 1.0671x; 1.0671x over previous
//
#include <hip/hip_runtime.h>
#include <hip/hip_fp16.h>

#define NEG_SLOPE 0.01f
typedef unsigned int uint;
typedef unsigned short u16;

#define NBK 256          // max buckets (N <= 65536); actual = ceil(N/256)
#define CHUNK 4096       // edges per partition workgroup
#define KPT 16           // edges per thread (CHUNK/256)
#define GROWS 16         // rows per wave in the register GEMMs

__device__ __forceinline__ float wbits(uint rec) {
    u16 b = (u16)(rec >> 16);
    __half h;
    *reinterpret_cast<u16*>(&h) = b;
    return __half2float(h);
}

// unpack uint4 (8 halves) and FMA into 8 accumulators
__device__ __forceinline__ void acc8(uint4 v, float w, float* a) {
    float2 f;
    f = __half22float2(*reinterpret_cast<__half2*>(&v.x)); a[0] = fmaf(f.x, w, a[0]); a[1] = fmaf(f.y, w, a[1]);
    f = __half22float2(*reinterpret_cast<__half2*>(&v.y)); a[2] = fmaf(f.x, w, a[2]); a[3] = fmaf(f.y, w, a[3]);
    f = __half22float2(*reinterpret_cast<__half2*>(&v.z)); a[4] = fmaf(f.x, w, a[4]); a[5] = fmaf(f.y, w, a[5]);
    f = __half22float2(*reinterpret_cast<__half2*>(&v.w)); a[6] = fmaf(f.x, w, a[6]); a[7] = fmaf(f.y, w, a[7]);
}

__device__ __forceinline__ void unpack8(uint4 v, float* s) {
    float2 f;
    f = __half22float2(*reinterpret_cast<__half2*>(&v.x)); s[0] = f.x; s[1] = f.y;
    f = __half22float2(*reinterpret_cast<__half2*>(&v.y)); s[2] = f.x; s[3] = f.y;
    f = __half22float2(*reinterpret_cast<__half2*>(&v.z)); s[4] = f.x; s[5] = f.y;
    f = __half22float2(*reinterpret_cast<__half2*>(&v.w)); s[6] = f.x; s[7] = f.y;
}

// ---- fused: register GEMM1 (fp32 in -> fp16 planes) + per-chunk histogram ----
__global__ __launch_bounds__(256) void gemm1_hist(const float* __restrict__ X,
                                                  const float* __restrict__ W,
                                                  __half* __restrict__ H, int N,
                                                  const int* __restrict__ dst,
                                                  uint* __restrict__ hist, int E,
                                                  int gblocks) {
    __shared__ uint lh[NBK];
    if ((int)blockIdx.x >= gblocks) {
        int cb = (int)blockIdx.x - gblocks;
        int t = threadIdx.x;
        lh[t] = 0u;
        __syncthreads();
        int base = cb * CHUNK;
#pragma unroll
        for (int r = 0; r < 4; ++r) {
            int e4 = base + r * 1024 + t * 4;
            if (e4 + 3 < E) {
                int4 d = *(const int4*)(dst + e4);
                atomicAdd(&lh[((uint)d.x) >> 8], 1u);
                atomicAdd(&lh[((uint)d.y) >> 8], 1u);
                atomicAdd(&lh[((uint)d.z) >> 8], 1u);
                atomicAdd(&lh[((uint)d.w) >> 8], 1u);
            } else {
                for (int e = e4; e < E && e < e4 + 4; ++e)
                    atomicAdd(&lh[((uint)dst[e]) >> 8], 1u);
            }
        }
        __syncthreads();
        hist[(size_t)cb * NBK + t] = lh[t];
        return;
    }
    // ---- GEMM part ----
    int lane = threadIdx.x & 63;
    int wv = threadIdx.x >> 6;
    float wc[64];
#pragma unroll
    for (int k = 0; k < 64; ++k) wc[k] = W[k * 64 + lane];
    size_t plane = (size_t)(lane >> 5) * ((size_t)N * 32);
    int c = lane & 31;
    int rowBase = ((int)blockIdx.x * 4 + wv) * GROWS;
    for (int g = 0; g < GROWS; g += 4) {
        int r0 = __builtin_amdgcn_readfirstlane(rowBase + g);
        if (r0 >= N) return;
        int e1 = min(r0 + 1, N - 1), e2 = min(r0 + 2, N - 1), e3 = min(r0 + 3, N - 1);
        const float* x0 = X + (size_t)r0 * 64;
        const float* x1 = X + (size_t)e1 * 64;
        const float* x2 = X + (size_t)e2 * 64;
        const float* x3 = X + (size_t)e3 * 64;
        float a0 = 0.f, a1 = 0.f, a2 = 0.f, a3 = 0.f;
        float b0 = 0.f, b1 = 0.f, b2 = 0.f, b3 = 0.f;
#pragma unroll
        for (int k = 0; k < 64; k += 2) {
            a0 = fmaf(x0[k], wc[k], a0); b0 = fmaf(x0[k + 1], wc[k + 1], b0);
            a1 = fmaf(x1[k], wc[k], a1); b1 = fmaf(x1[k + 1], wc[k + 1], b1);
            a2 = fmaf(x2[k], wc[k], a2); b2 = fmaf(x2[k + 1], wc[k + 1], b2);
            a3 = fmaf(x3[k], wc[k], a3); b3 = fmaf(x3[k + 1], wc[k + 1], b3);
        }
        H[plane + (size_t)r0 * 32 + c] = __float2half(a0 + b0);
        if (r0 + 1 < N) H[plane + (size_t)(r0 + 1) * 32 + c] = __float2half(a1 + b1);
        if (r0 + 2 < N) H[plane + (size_t)(r0 + 2) * 32 + c] = __float2half(a2 + b2);
        if (r0 + 3 < N) H[plane + (size_t)(r0 + 3) * 32 + c] = __float2half(a3 + b3);
    }
}

// ---- S1: per-bucket column scan of hist (one block per bucket) -> chunk prefixes + buckTotal ----
__global__ __launch_bounds__(256) void scan_hist(uint* __restrict__ hist,
                                                 uint* __restrict__ buckTotal,
                                                 int nchunks) {
    __shared__ uint lds[256];
    int b = blockIdx.x;
    int t = threadIdx.x;
    uint carry = 0;
    for (int c0 = 0; c0 < nchunks; c0 += 256) {
        int c = c0 + t;
        uint v = (c < nchunks) ? hist[(size_t)c * NBK + b] : 0u;
        lds[t] = v;
        __syncthreads();
        for (int off = 1; off < 256; off <<= 1) {
            uint u = (t >= off) ? lds[t - off] : 0u;
            __syncthreads();
            lds[t] += u;
            __syncthreads();
        }
        uint incl = lds[t];
        if (c < nchunks) hist[(size_t)c * NBK + b] = carry + incl - v;
        uint tot = lds[255];
        __syncthreads();
        carry += tot;
    }
    if (t == 0) buckTotal[b] = carry;
}

// ---- P: partition edges into reserved bucket runs; bases from buckTotal LDS scan ----
__global__ __launch_bounds__(256) void partition_edges(const int* __restrict__ src,
                                                       const int* __restrict__ dst,
                                                       const uint* __restrict__ hist,
                                                       const uint* __restrict__ buckTotal,
                                                       uint* __restrict__ staging,
                                                       int E) {
    __shared__ uint lh[NBK];
    __shared__ uint sc[NBK];
    __shared__ uint runbase[NBK];
    int t = threadIdx.x;
    lh[t] = 0u;
    uint tot = buckTotal[t];
    sc[t] = tot;
    __syncthreads();
    for (int off = 1; off < NBK; off <<= 1) {
        uint u = (t >= off) ? sc[t - off] : 0u;
        __syncthreads();
        sc[t] += u;
        __syncthreads();
    }
    int base = blockIdx.x * CHUNK;
    uint rec[KPT], rb[KPT], rk[KPT];
#pragma unroll
    for (int r = 0; r < 4; ++r) {
        int e4 = base + r * 1024 + t * 4;
        if (e4 + 3 < E) {
            int4 s = *(const int4*)(src + e4);
            int4 d = *(const int4*)(dst + e4);
            int k = r * 4;
            rb[k + 0] = ((uint)d.x) >> 8; rec[k + 0] = (uint)s.x | (((uint)d.x & 255u) << 16);
            rb[k + 1] = ((uint)d.y) >> 8; rec[k + 1] = (uint)s.y | (((uint)d.y & 255u) << 16);
            rb[k + 2] = ((uint)d.z) >> 8; rec[k + 2] = (uint)s.z | (((uint)d.z & 255u) << 16);
            rb[k + 3] = ((uint)d.w) >> 8; rec[k + 3] = (uint)s.w | (((uint)d.w & 255u) << 16);
            rk[k + 0] = atomicAdd(&lh[rb[k + 0]], 1u);
            rk[k + 1] = atomicAdd(&lh[rb[k + 1]], 1u);
            rk[k + 2] = atomicAdd(&lh[rb[k + 2]], 1u);
            rk[k + 3] = atomicAdd(&lh[rb[k + 3]], 1u);
        } else {
            for (int j = 0; j < 4; ++j) {
                int e = e4 + j;
                int k = r * 4 + j;
                if (e < E) {
                    uint s = (uint)src[e], d = (uint)dst[e];
                    rb[k] = d >> 8;
                    rec[k] = s | ((d & 255u) << 16);
                    rk[k] = atomicAdd(&lh[rb[k]], 1u);
                } else rb[k] = 0xFFFFFFFFu;
            }
        }
    }
    __syncthreads();
    runbase[t] = (sc[t] - tot) + hist[(size_t)blockIdx.x * NBK + t];
    __syncthreads();
#pragma unroll
    for (int k = 0; k < KPT; ++k)
        if (rb[k] != 0xFFFFFFFFu)
            staging[runbase[rb[k]] + rk[k]] = rec[k];
}

// ---- B: per-bucket CSR build: srcIdx (u16), offs, dinv; base from buckTotal LDS scan ----
__global__ __launch_bounds__(256) void build_csr(const uint* __restrict__ staging,
                                                 const uint* __restrict__ buckTotal,
                                                 u16* __restrict__ srcIdx,
                                                 uint* __restrict__ offs,
                                                 float* __restrict__ dinv,
                                                 int N, int nbuck) {
    __shared__ uint nh[256];
    __shared__ uint nstart[256];
    __shared__ u16 rankbuf[8192];
    __shared__ u16 outbuf[8192];
    int b = blockIdx.x;
    int t = threadIdx.x;
    uint tot = buckTotal[t];
    nstart[t] = tot;
    __syncthreads();
    for (int off = 1; off < NBK; off <<= 1) {
        uint u = (t >= off) ? nstart[t - off] : 0u;
        __syncthreads();
        nstart[t] += u;
        __syncthreads();
    }
    uint endb = nstart[b];
    uint base = endb - buckTotal[b];
    __syncthreads();
    uint T = endb - base;
    nh[t] = 0u;
    __syncthreads();
    for (uint i = t; i < T; i += 256) {
        uint rec = staging[base + i];
        rankbuf[i] = (u16)atomicAdd(&nh[(rec >> 16) & 255u], 1u);
    }
    __syncthreads();
    uint deg = nh[t];
    nstart[t] = deg;
    __syncthreads();
    for (int off = 1; off < 256; off <<= 1) {
        uint u = (t >= off) ? nstart[t - off] : 0u;
        __syncthreads();
        nstart[t] += u;
        __syncthreads();
    }
    uint excl = nstart[t] - deg;
    __syncthreads();
    nstart[t] = excl;
    __syncthreads();
    for (uint i = t; i < T; i += 256) {
        uint rec = staging[base + i];
        outbuf[nstart[(rec >> 16) & 255u] + rankbuf[i]] = (u16)(rec & 0xFFFFu);
    }
    __syncthreads();
    for (uint i = t; i < T; i += 256) srcIdx[base + i] = outbuf[i];
    int node = b * 256 + t;
    if (node < N) {
        offs[node] = base + excl;
        dinv[node] = rsqrtf((float)(deg + 1u));
    }
    if (b == nbuck - 1 && t == 0) offs[N] = endb;
}

// ---- packed[p] = srcIdx[p] | fp16(dinv[srcIdx[p]])<<16 ----
__global__ __launch_bounds__(256) void fill_pack(const u16* __restrict__ srcIdx,
                                                 const float* __restrict__ dinv,
                                                 uint* __restrict__ packed, int E) {
    int i4 = (blockIdx.x * 256 + threadIdx.x) * 4;
    if (i4 + 3 < E) {
        ushort4 s = *(const ushort4*)(srcIdx + i4);
        uint4 o;
        __half h0 = __float2half(dinv[s.x]);
        __half h1 = __float2half(dinv[s.y]);
        __half h2 = __float2half(dinv[s.z]);
        __half h3 = __float2half(dinv[s.w]);
        o.x = (uint)s.x | ((uint)*reinterpret_cast<u16*>(&h0) << 16);
        o.y = (uint)s.y | ((uint)*reinterpret_cast<u16*>(&h1) << 16);
        o.z = (uint)s.z | ((uint)*reinterpret_cast<u16*>(&h2) << 16);
        o.w = (uint)s.w | ((uint)*reinterpret_cast<u16*>(&h3) << 16);
        *(uint4*)(packed + i4) = o;
    } else {
        for (int i = i4; i < E; ++i) {
            __half h = __float2half(dinv[srcIdx[i]]);
            packed[i] = (uint)srcIdx[i] | ((uint)*reinterpret_cast<u16*>(&h) << 16);
        }
    }
}

// ---------------- layer-1 aggregation: 4-lane group per node, 16 nodes/wave, no shuffles ----
// grid = 2*nbA; blocks [0,nbA) plane 0, [nbA,2*nbA) plane 1. 64 nodes/block.
__global__ __launch_bounds__(256) void agg1(const __half* __restrict__ h,
                                            const uint* __restrict__ offs,
                                            const uint* __restrict__ packed,
                                            const float* __restrict__ dinv,
                                            const float* __restrict__ b,
                                            const float* __restrict__ mask,
                                            __half* __restrict__ outp,
                                            int N, int nbA) {
    int pl = ((int)blockIdx.x >= nbA) ? 1 : 0;
    int blk = (int)blockIdx.x - pl * nbA;
    int lane = threadIdx.x & 63;
    int wid = threadIdx.x >> 6;
    int g = lane >> 2;
    int q = lane & 3;
    int node = blk * 64 + wid * 16 + g;
    bool valid = node < N;
    uint beg = 0, end = 0;
    if (valid) { beg = offs[node]; end = offs[node + 1]; }
    const uint4* h8 = (const uint4*)(h + (size_t)pl * N * 32);
    float a[8] = {0.f, 0.f, 0.f, 0.f, 0.f, 0.f, 0.f, 0.f};
    uint p = beg;
    for (; p + 3 < end; p += 4) {
        uint e0 = packed[p], e1 = packed[p + 1], e2 = packed[p + 2], e3 = packed[p + 3];
        uint4 v0 = h8[(size_t)(e0 & 0xFFFFu) * 4 + q];
        uint4 v1 = h8[(size_t)(e1 & 0xFFFFu) * 4 + q];
        uint4 v2 = h8[(size_t)(e2 & 0xFFFFu) * 4 + q];
        uint4 v3 = h8[(size_t)(e3 & 0xFFFFu) * 4 + q];
        acc8(v0, wbits(e0), a);
        acc8(v1, wbits(e1), a);
        acc8(v2, wbits(e2), a);
        acc8(v3, wbits(e3), a);
    }
    for (; p < end; ++p) {
        uint e0 = packed[p];
        uint4 v0 = h8[(size_t)(e0 & 0xFFFFu) * 4 + q];
        acc8(v0, wbits(e0), a);
    }
    if (valid) {
        float dv = dinv[node];
        float dv2 = dv * dv;
        float s[8];
        unpack8(h8[(size_t)node * 4 + q], s);
        const float4* b4 = (const float4*)b;
        float4 bv0 = b4[pl * 8 + q * 2];
        float4 bv1 = b4[pl * 8 + q * 2 + 1];
        const float4* m4 = (const float4*)mask;
        float4 mv0 = m4[(size_t)node * 16 + pl * 8 + q * 2];
        float4 mv1 = m4[(size_t)node * 16 + pl * 8 + q * 2 + 1];
        float bb[8] = {bv0.x, bv0.y, bv0.z, bv0.w, bv1.x, bv1.y, bv1.z, bv1.w};
        float mm[8] = {mv0.x, mv0.y, mv0.z, mv0.w, mv1.x, mv1.y, mv1.z, mv1.w};
        uint4 o;
        uint* op = (uint*)&o;
#pragma unroll
        for (int i = 0; i < 4; ++i) {
            float v0 = a[2 * i] * dv + s[2 * i] * dv2 + bb[2 * i];
            float v1 = a[2 * i + 1] * dv + s[2 * i + 1] * dv2 + bb[2 * i + 1];
            v0 = (v0 > 0.f) ? v0 : NEG_SLOPE * v0;
            v1 = (v1 > 0.f) ? v1 : NEG_SLOPE * v1;
            v0 *= mm[2 * i]; v1 *= mm[2 * i + 1];
            __half2 hh = __floats2half2_rn(v0, v1);
            op[i] = *reinterpret_cast<uint*>(&hh);
        }
        ((uint4*)(outp + (size_t)pl * N * 32))[(size_t)node * 4 + q] = o;
    }
}

// ---------------- register GEMM 2: fp16 plane input (uniform scalar reads), fp16 out ----------------
__global__ __launch_bounds__(256) void gemm64x32(const __half* __restrict__ Xh,
                                                 const float* __restrict__ W,
                                                 __half* __restrict__ H, int N) {
    int lane = threadIdx.x & 63;
    int col = lane & 31;
    int wv = threadIdx.x >> 6;
    size_t N32 = (size_t)N * 32;
    float wc[64];
#pragma unroll
    for (int k = 0; k < 64; ++k) wc[k] = W[k * 32 + col];
    int rowBase = ((int)blockIdx.x * 4 + wv) * GROWS;
    for (int g = 0; g < GROWS; g += 4) {
        int r0 = __builtin_amdgcn_readfirstlane(rowBase + g);
        if (r0 >= N) return;
        int e1 = min(r0 + 1, N - 1), e2 = min(r0 + 2, N - 1), e3 = min(r0 + 3, N - 1);
        float a0 = 0.f, a1 = 0.f, a2 = 0.f, a3 = 0.f;
        float b0 = 0.f, b1 = 0.f, b2 = 0.f, b3 = 0.f;
#pragma unroll
        for (int pl = 0; pl < 2; ++pl) {
            const uint* x0 = (const uint*)(Xh + pl * N32 + (size_t)r0 * 32);
            const uint* x1 = (const uint*)(Xh + pl * N32 + (size_t)e1 * 32);
            const uint* x2 = (const uint*)(Xh + pl * N32 + (size_t)e2 * 32);
            const uint* x3 = (const uint*)(Xh + pl * N32 + (size_t)e3 * 32);
#pragma unroll
            for (int kk = 0; kk < 16; ++kk) {
                uint u0 = x0[kk], u1 = x1[kk], u2 = x2[kk], u3 = x3[kk];
                float2 f0 = __half22float2(*reinterpret_cast<__half2*>(&u0));
                float2 f1 = __half22float2(*reinterpret_cast<__half2*>(&u1));
                float2 f2 = __half22float2(*reinterpret_cast<__half2*>(&u2));
                float2 f3 = __half22float2(*reinterpret_cast<__half2*>(&u3));
                int k0 = pl * 32 + 2 * kk;
                a0 = fmaf(f0.x, wc[k0], a0); b0 = fmaf(f0.y, wc[k0 + 1], b0);
                a1 = fmaf(f1.x, wc[k0], a1); b1 = fmaf(f1.y, wc[k0 + 1], b1);
                a2 = fmaf(f2.x, wc[k0], a2); b2 = fmaf(f2.y, wc[k0 + 1], b2);
                a3 = fmaf(f3.x, wc[k0], a3); b3 = fmaf(f3.y, wc[k0 + 1], b3);
            }
        }
        if (lane < 32) {
            H[(size_t)r0 * 32 + col] = __float2half(a0 + b0);
            if (r0 + 1 < N) H[(size_t)(r0 + 1) * 32 + col] = __float2half(a1 + b1);
            if (r0 + 2 < N) H[(size_t)(r0 + 2) * 32 + col] = __float2half(a2 + b2);
            if (r0 + 3 < N) H[(size_t)(r0 + 3) * 32 + col] = __float2half(a3 + b3);
        }
    }
}

// ---------------- layer-2 aggregation: 4-lane group per node, 16 nodes/wave, no shuffles ----
__global__ __launch_bounds__(256) void agg2(const __half* __restrict__ h,
                                            const uint* __restrict__ offs,
                                            const uint* __restrict__ packed,
                                            const float* __restrict__ dinv,
                                            const float* __restrict__ b,
                                            float* __restrict__ outp, int N) {
    int lane = threadIdx.x & 63;
    int wid = threadIdx.x >> 6;
    int g = lane >> 2;
    int q = lane & 3;
    int node = (int)blockIdx.x * 64 + wid * 16 + g;
    bool valid = node < N;
    uint beg = 0, end = 0;
    if (valid) { beg = offs[node]; end = offs[node + 1]; }
    const uint4* h8 = (const uint4*)h;
    float a[8] = {0.f, 0.f, 0.f, 0.f, 0.f, 0.f, 0.f, 0.f};
    uint p = beg;
    for (; p + 3 < end; p += 4) {
        uint e0 = packed[p], e1 = packed[p + 1], e2 = packed[p + 2], e3 = packed[p + 3];
        uint4 v0 = h8[(size_t)(e0 & 0xFFFFu) * 4 + q];
        uint4 v1 = h8[(size_t)(e1 & 0xFFFFu) * 4 + q];
        uint4 v2 = h8[(size_t)(e2 & 0xFFFFu) * 4 + q];
        uint4 v3 = h8[(size_t)(e3 & 0xFFFFu) * 4 + q];
        acc8(v0, wbits(e0), a);
        acc8(v1, wbits(e1), a);
        acc8(v2, wbits(e2), a);
        acc8(v3, wbits(e3), a);
    }
    for (; p < end; ++p) {
        uint e0 = packed[p];
        uint4 v0 = h8[(size_t)(e0 & 0xFFFFu) * 4 + q];
        acc8(v0, wbits(e0), a);
    }
    if (valid) {
        float dv = dinv[node];
        float dv2 = dv * dv;
        float s[8];
        unpack8(h8[(size_t)node * 4 + q], s);
        float4 bv0 = ((const float4*)b)[q * 2];
        float4 bv1 = ((const float4*)b)[q * 2 + 1];
        float bb[8] = {bv0.x, bv0.y, bv0.z, bv0.w, bv1.x, bv1.y, bv1.z, bv1.w};
        float o[8];
#pragma unroll
        for (int i = 0; i < 8; ++i) {
            float v = a[i] * dv + s[i] * dv2 + bb[i];
            o[i] = (v > 0.f) ? v : NEG_SLOPE * v;
        }
        float4* outv = (float4*)outp;
        outv[(size_t)node * 8 + q * 2]     = make_float4(o[0], o[1], o[2], o[3]);
        outv[(size_t)node * 8 + q * 2 + 1] = make_float4(o[4], o[5], o[6], o[7]);
    }
}

extern "C" void kernel_launch(void* const* d_in, const int* in_sizes, int n_in,
                              void* d_out, int out_size, void* d_ws, size_t ws_size,
                              hipStream_t stream) {
    const float* x    = (const float*)d_in[0];
    const int*   ei   = (const int*)d_in[1];
    const float* mask = (const float*)d_in[2];
    const float* W1   = (const float*)d_in[3];
    const float* b1   = (const float*)d_in[4];
    const float* W2   = (const float*)d_in[5];
    const float* b2   = (const float*)d_in[6];
    float* out = (float*)d_out;

    const int N = in_sizes[0] / 64;   // 50000 (< 65536: u16 CSR valid)
    const int E = in_sizes[1] / 2;    // 800000
    const int* src = ei;
    const int* dst = ei + E;

    const int nbuck  = (N + 255) >> 8;
    const int chunks = (E + CHUNK - 1) / CHUNK;
    const int gblocks = (N + 4 * GROWS - 1) / (4 * GROWS);
    const int nbA = (N + 63) / 64;    // agg blocks (64 nodes each)

    char* w = (char*)d_ws;
    uint*  hist      = (uint*)w;    w += (size_t)chunks * NBK * 4;
    uint*  buckTotal = (uint*)w;    w += NBK * 4;
    w = (char*)(((size_t)w + 15) & ~15ull);
    uint*  offs      = (uint*)w;    w += (size_t)(N + 1) * 4;
    w = (char*)(((size_t)w + 15) & ~15ull);
    float* dinv      = (float*)w;   w += (size_t)N * 4;
    uint*  staging   = (uint*)w;    w += (size_t)E * 4;
    u16*   srcIdx    = (u16*)w;     w += (((size_t)E * 2 + 15) & ~15ull);
    uint*  packed    = (uint*)w;    w += (size_t)E * 4;
    __half* h1       = (__half*)w;  w += (size_t)N * 64 * 2;   // 2 planes of N*32
    __half* hpost    = (__half*)w;  w += (size_t)N * 64 * 2;   // 2 planes of N*32
    __half* h2       = h1;  // reuse: h1 dead after agg1

    // ---- prep + gemm1 fused; parallel scan; deterministic counting sort ----
    gemm1_hist<<<gblocks + chunks, 256, 0, stream>>>(x, W1, h1, N, dst, hist, E, gblocks);
    scan_hist<<<NBK, 256, 0, stream>>>(hist, buckTotal, chunks);
    partition_edges<<<chunks, 256, 0, stream>>>(src, dst, hist, buckTotal, staging, E);
    build_csr<<<nbuck, 256, 0, stream>>>(staging, buckTotal, srcIdx, offs, dinv, N, nbuck);
    fill_pack<<<(E + 1023) / 1024, 256, 0, stream>>>(srcIdx, dinv, packed, E);

    // ---- layer 1 aggregation (plane-split, group-per-node) ----
    agg1<<<2 * nbA, 256, 0, stream>>>(h1, offs, packed, dinv, b1, mask, hpost, N, nbA);

    // ---- layer 2 ----
    gemm64x32<<<gblocks, 256, 0, stream>>>(hpost, W2, h2, N);
    agg2<<<nbA, 256, 0, stream>>>(h2, offs, packed, dinv, b2, out, N);
}